// Round 4
// baseline (115.360 us; speedup 1.0000x reference)
//
#include <hip/hip_runtime.h>
#include <hip/hip_cooperative_groups.h>
#include <math.h>

namespace cg = cooperative_groups;

#define N 4096
#define RPB 16          // rows per block
#define NBLK 256        // blocks = N / RPB
#define FEPS 1e-7f

// ---------------------------------------------------------------------------
// ws layout (bytes):
//   [0,8)            double wd (focal mean)
//   [16,20)          int    counter
//   [64, 64+4K)      double pg[512]   (gA partials [0..255], gB [256..511])
//   [4160, +6K)      double pr[768]   (AB [0..255], AA [256..511], BB [512..767])
//   [10304, +16K)    float rowA[N]
//   [26688, +16K)    float rowB[N]
// ---------------------------------------------------------------------------

__device__ __forceinline__ double block_reduce(double v) {
    __shared__ double buf[4];
    int tid = threadIdx.x;
    #pragma unroll
    for (int o = 32; o > 0; o >>= 1) v += __shfl_down(v, o, 64);
    __syncthreads();
    if ((tid & 63) == 0) buf[tid >> 6] = v;
    __syncthreads();
    return buf[0] + buf[1] + buf[2] + buf[3];
}

__global__ __launch_bounds__(256) void fused(
        const float* __restrict__ target,
        const float* __restrict__ output,
        const float* __restrict__ y_class,
        const float* __restrict__ y_pred_class,
        const float* __restrict__ v1,
        const float* __restrict__ v2,
        const float* __restrict__ w,
        const int* __restrict__ power,
        int* __restrict__ counter,
        float* __restrict__ rowA,
        float* __restrict__ rowB,
        double* __restrict__ pg,
        double* __restrict__ pr,
        double* __restrict__ wd,
        float* __restrict__ out) {
    cg::grid_group grid = cg::this_grid();
    __shared__ float s1[N], s2[N], sw[N];       // 48 KiB, persists both passes
    __shared__ float sav[N], sbv[N];            // 32 KiB, pass 2
    __shared__ float rsA[RPB], rsB[RPB];
    int tid = threadIdx.x;
    int b   = blockIdx.x;

    if (b == 0 && tid == 0) *counter = 0;

    // ---- stage inputs (once; reused by both passes) ----
    for (int t = tid * 4; t < N; t += 1024) {
        *(float4*)&s1[t] = *(const float4*)&v1[t];
        *(float4*)&s2[t] = *(const float4*)&v2[t];
        *(float4*)&sw[t] = *(const float4*)&w [t];
    }
    __syncthreads();

    // ---- focal BCE on block 255 (others proceed straight to pass 1) ----
    if (b == NBLK - 1) {
        double s_ypc = 0.0, s_ypc2 = 0.0, s_yc = 0.0;
        for (int i = tid; i < N; i += 256) {
            float ypc = y_pred_class[i];
            s_ypc  += (double)ypc;
            s_ypc2 += (double)ypc * (double)ypc;
            s_yc   += (double)y_class[i];
        }
        double t_ypc  = block_reduce(s_ypc);
        double t_ypc2 = block_reduce(s_ypc2);
        double t_yc   = block_reduce(s_yc);

        __shared__ float  sm, sinv2s;
        __shared__ double s_sum1myc;
        if (tid == 0) {
            double m   = t_ypc / (double)N;
            double var = t_ypc2 / (double)N - m * m;
            double sd  = sqrt(var > 0.0 ? var : 0.0);
            sm     = (float)m;
            sinv2s = (float)(1.0 / (2.0 * sd));
            s_sum1myc = (double)N - t_yc;
        }
        __syncthreads();

        float m = sm, inv2s = sinv2s;
        double s_cwf = 0.0, s_cwfb = 0.0;
        for (int i = tid; i < N; i += 256) {
            float yc  = y_class[i];
            float ypc = y_pred_class[i];
            float nrm = (ypc - m) * inv2s + 0.5f;
            nrm = fminf(fmaxf(nrm, 0.0f), 1.0f);
            float c1  = (1.0f - yc) * nrm;
            float cwf = c1 * c1;                    // GAMMA = 2
            float x = fminf(fmaxf(output[i], FEPS), 1.0f - FEPS);
            float t = target[i];
            float bce = -t * logf(x) - (1.0f - t) * logf(1.0f - x);
            s_cwf  += (double)cwf;
            s_cwfb += (double)cwf * (double)bce;
        }
        double t_cwf  = block_reduce(s_cwf);
        double t_cwfb = block_reduce(s_cwfb);
        if (tid == 0) wd[0] = t_cwfb * (s_sum1myc / t_cwf) / (double)N;
    }

    // ---- pass 1: 2 rows/thread, 32 j-lanes/row ----
    int lane = tid & 31;
    int g    = tid >> 5;                 // 8 groups
    int i0   = b * RPB + g * 2;
    float a0 = s1[i0], a1 = s1[i0 + 1];
    float e0 = s2[i0], e1 = s2[i0 + 1];
    float sa0 = 0.f, sa1 = 0.f, sb0 = 0.f, sb1 = 0.f;
    #pragma unroll 4
    for (int k = 0; k < N / (32 * 4); ++k) {     // 32 float4 steps
        int j = 4 * lane + 128 * k;
        float4 x1 = *(const float4*)&s1[j];
        float4 x2 = *(const float4*)&s2[j];
        float4 xw = *(const float4*)&sw[j];
        #define P1(c)                                  \
        {                                              \
            sa0 = fmaf(fabsf(a0 - x1.c), xw.c, sa0);   \
            sa1 = fmaf(fabsf(a1 - x1.c), xw.c, sa1);   \
            sb0 = fmaf(fabsf(e0 - x2.c), xw.c, sb0);   \
            sb1 = fmaf(fabsf(e1 - x2.c), xw.c, sb1);   \
        }
        P1(x) P1(y) P1(z) P1(w)
        #undef P1
    }
    #pragma unroll
    for (int o = 1; o < 32; o <<= 1) {
        sa0 += __shfl_xor(sa0, o, 32);
        sa1 += __shfl_xor(sa1, o, 32);
        sb0 += __shfl_xor(sb0, o, 32);
        sb1 += __shfl_xor(sb1, o, 32);
    }
    if (lane == 0) {
        rowA[i0] = sa0; rowA[i0 + 1] = sa1;
        rowB[i0] = sb0; rowB[i0 + 1] = sb1;
        rsA[g * 2] = sa0; rsA[g * 2 + 1] = sa1;
        rsB[g * 2] = sb0; rsB[g * 2 + 1] = sb1;
    }
    __syncthreads();
    if (tid == 0) {
        double ga = 0.0, gb = 0.0;
        #pragma unroll
        for (int q = 0; q < RPB; ++q) {
            double wq = (double)sw[b * RPB + q];
            ga += (double)rsA[q] * wq;
            gb += (double)rsB[q] * wq;
        }
        pg[b] = ga; pg[NBLK + b] = gb;
    }
    __threadfence();
    grid.sync();
    __threadfence();

    // ---- grand means (redundant per block; 4KB L2 broadcast) ----
    const double NN = (double)N * (double)N;
    float gA = (float)(block_reduce(pg[tid]) / NN);
    float gB = (float)(block_reduce(pg[NBLK + tid]) / NN);

    // ---- stage row means ----
    const float invN = 1.0f / (float)N;
    for (int t = tid * 4; t < N; t += 1024) {
        float4 ra = *(const float4*)&rowA[t];
        float4 rb = *(const float4*)&rowB[t];
        ra.x *= invN; ra.y *= invN; ra.z *= invN; ra.w *= invN;
        rb.x *= invN; rb.y *= invN; rb.z *= invN; rb.w *= invN;
        *(float4*)&sav[t] = ra;
        *(float4*)&sbv[t] = rb;
    }
    __syncthreads();

    // ---- pass 2 ----
    float cA0 = sav[i0]     - gA;
    float cA1 = sav[i0 + 1] - gA;
    float cB0 = sbv[i0]     - gB;
    float cB1 = sbv[i0 + 1] - gB;

    float ab0 = 0.f, aa0 = 0.f, bb0 = 0.f;
    float ab1 = 0.f, aa1 = 0.f, bb1 = 0.f;
    #pragma unroll 4
    for (int k = 0; k < N / (32 * 4); ++k) {     // 32 float4 steps
        int j = 4 * lane + 128 * k;
        float4 x1 = *(const float4*)&s1[j];
        float4 x2 = *(const float4*)&s2[j];
        float4 xw = *(const float4*)&sw[j];
        float4 xa = *(const float4*)&sav[j];
        float4 xb = *(const float4*)&sbv[j];
        #define P2(c)                                            \
        {                                                        \
            float Am0 = fabsf(a0 - x1.c) - xa.c - cA0;           \
            float Bm0 = fabsf(e0 - x2.c) - xb.c - cB0;           \
            float Am1 = fabsf(a1 - x1.c) - xa.c - cA1;           \
            float Bm1 = fabsf(e1 - x2.c) - xb.c - cB1;           \
            float Aw0 = Am0 * xw.c, Bw0 = Bm0 * xw.c;            \
            float Aw1 = Am1 * xw.c, Bw1 = Bm1 * xw.c;            \
            ab0 = fmaf(Aw0, Bm0, ab0);                           \
            aa0 = fmaf(Aw0, Am0, aa0);                           \
            bb0 = fmaf(Bw0, Bm0, bb0);                           \
            ab1 = fmaf(Aw1, Bm1, ab1);                           \
            aa1 = fmaf(Aw1, Am1, aa1);                           \
            bb1 = fmaf(Bw1, Bm1, bb1);                           \
        }
        P2(x) P2(y) P2(z) P2(w)
        #undef P2
    }
    #pragma unroll
    for (int o = 1; o < 32; o <<= 1) {
        ab0 += __shfl_xor(ab0, o, 32);
        aa0 += __shfl_xor(aa0, o, 32);
        bb0 += __shfl_xor(bb0, o, 32);
        ab1 += __shfl_xor(ab1, o, 32);
        aa1 += __shfl_xor(aa1, o, 32);
        bb1 += __shfl_xor(bb1, o, 32);
    }
    __shared__ double rd[3][RPB];
    if (lane == 0) {
        double w0 = (double)sw[i0], w1 = (double)sw[i0 + 1];
        rd[0][g * 2] = fabs((double)ab0) * w0;  rd[0][g * 2 + 1] = fabs((double)ab1) * w1;
        rd[1][g * 2] = (double)aa0 * w0;        rd[1][g * 2 + 1] = (double)aa1 * w1;
        rd[2][g * 2] = (double)bb0 * w0;        rd[2][g * 2 + 1] = (double)bb1 * w1;
    }
    __syncthreads();
    if (tid == 0) {
        double tab = 0.0, taa = 0.0, tbb = 0.0;
        #pragma unroll
        for (int q = 0; q < RPB; ++q) { tab += rd[0][q]; taa += rd[1][q]; tbb += rd[2][q]; }
        pr[b] = tab; pr[NBLK + b] = taa; pr[2 * NBLK + b] = tbb;
    }

    // ---- last-block-done final reduction ----
    __shared__ int isLast;
    if (tid == 0) {
        __threadfence();
        isLast = (atomicAdd(counter, 1) == NBLK - 1);
    }
    __syncthreads();
    if (!isLast) return;
    __threadfence();

    double tab = block_reduce(pr[tid]);
    double taa = block_reduce(pr[NBLK + tid]);
    double tbb = block_reduce(pr[2 * NBLK + tid]);
    if (tid == 0) {
        double mAB = tab / NN;
        double mAA = taa / NN;
        double mBB = tbb / NN;
        int p = power[0];
        double d;
        if (p == 1) {
            d = mAB / sqrt(fabs(mAA * mBB) + 1e-12);
        } else if (p == 2) {
            d = (mAB * mAB) / (fabs(mAA * mBB) + 1e-12);
        } else {
            d = pow(mAB / sqrt(mAA * mBB) + 1e-12, (double)p);
        }
        if (isnan(d)) d = 0.0;
        if (d < 0.0)  d = 0.0;
        out[0] = (float)(wd[0] + 1000.0 * d);
    }
}

// ---------------------------------------------------------------------------
extern "C" void kernel_launch(void* const* d_in, const int* in_sizes, int n_in,
                              void* d_out, int out_size, void* d_ws, size_t ws_size,
                              hipStream_t stream) {
    const float* target       = (const float*)d_in[0];
    const float* output       = (const float*)d_in[1];
    const float* y_class      = (const float*)d_in[2];
    const float* y_pred_class = (const float*)d_in[3];
    const float* var_1        = (const float*)d_in[4];
    const float* var_2        = (const float*)d_in[5];
    const float* normedweight = (const float*)d_in[6];
    const int*   power        = (const int*)d_in[7];
    float* out = (float*)d_out;

    char*   ws      = (char*)d_ws;
    double* wd      = (double*)ws;
    int*    counter = (int*)(ws + 16);
    double* pg      = (double*)(ws + 64);            // 512 doubles
    double* pr      = (double*)(ws + 64 + 4096);     // 768 doubles
    float*  rowA    = (float*)(ws + 64 + 4096 + 6144);
    float*  rowB    = rowA + N;

    void* args[] = { &target, &output, &y_class, &y_pred_class,
                     &var_1, &var_2, &normedweight, &power,
                     &counter, &rowA, &rowB, &pg, &pr, &wd, &out };
    hipLaunchCooperativeKernel((const void*)fused, dim3(NBLK), dim3(256),
                               args, 0, stream);
}

// Round 5
// 45.354 us; speedup vs baseline: 2.5435x; 2.5435x over previous
//
#include <hip/hip_runtime.h>
#include <math.h>

#define N     4096
#define NBLK  256
#define RPB   16          // rows per block
#define FEPS  1e-7f

// ---------------------------------------------------------------------------
// ws layout (bytes):
//   [0,4)    uint cntA (inter-phase barrier)   } zeroed by memset node
//   [4,8)    uint cntB (last-block-done)       }
//   [8,16)   double wd (focal mean)
//   [64, +4K)   double pg[512]  (gA partials [0..255], gB [256..511])
//   [4160,+6K)  double pr[768]  (AB, AA, BB per-block partials)
//   [10304,+16K) float rowA[N]
//   [26688,+16K) float rowB[N]
// ---------------------------------------------------------------------------

__device__ __forceinline__ double block_reduce(double v) {
    __shared__ double buf[4];
    int tid = threadIdx.x;
#pragma unroll
    for (int o = 32; o > 0; o >>= 1) v += __shfl_down(v, o, 64);
    __syncthreads();
    if ((tid & 63) == 0) buf[tid >> 6] = v;
    __syncthreads();
    return buf[0] + buf[1] + buf[2] + buf[3];
}

__global__ __launch_bounds__(256) void fused(
        const float* __restrict__ target,
        const float* __restrict__ output,
        const float* __restrict__ y_class,
        const float* __restrict__ y_pred_class,
        const float* __restrict__ v1,
        const float* __restrict__ v2,
        const float* __restrict__ w,
        const int*   __restrict__ power,
        unsigned int* __restrict__ cntA,
        unsigned int* __restrict__ cntB,
        double* __restrict__ wd,
        double* __restrict__ pg,
        double* __restrict__ pr,
        float*  __restrict__ rowA,
        float*  __restrict__ rowB,
        float*  __restrict__ out)
{
    __shared__ float s1[N], s2[N], sw[N];     // 48 KiB, persists both passes
    __shared__ float sav[N], sbv[N];          // 32 KiB, pass-2 row means
    __shared__ float rsA[RPB], rsB[RPB];
    __shared__ double rd[3][RPB];

    const int tid = threadIdx.x;
    const int b   = blockIdx.x;

    // ---- stage inputs once ----
    for (int t = tid * 4; t < N; t += 1024) {
        *(float4*)&s1[t] = *(const float4*)&v1[t];
        *(float4*)&s2[t] = *(const float4*)&v2[t];
        *(float4*)&sw[t] = *(const float4*)&w [t];
    }
    __syncthreads();

    // ---- focal BCE on block 255 (before its pass-1 share) ----
    if (b == NBLK - 1) {
        double s_ypc = 0.0, s_ypc2 = 0.0, s_yc = 0.0;
        for (int i = tid; i < N; i += 256) {
            float ypc = y_pred_class[i];
            s_ypc  += (double)ypc;
            s_ypc2 += (double)ypc * (double)ypc;
            s_yc   += (double)y_class[i];
        }
        double t_ypc  = block_reduce(s_ypc);
        double t_ypc2 = block_reduce(s_ypc2);
        double t_yc   = block_reduce(s_yc);

        __shared__ float  sm, sinv2s;
        __shared__ double s_sum1myc;
        if (tid == 0) {
            double m   = t_ypc / (double)N;
            double var = t_ypc2 / (double)N - m * m;
            double sd  = sqrt(var > 0.0 ? var : 0.0);
            sm     = (float)m;
            sinv2s = (float)(1.0 / (2.0 * sd));
            s_sum1myc = (double)N - t_yc;
        }
        __syncthreads();

        float m = sm, inv2s = sinv2s;
        double s_cwf = 0.0, s_cwfb = 0.0;
        for (int i = tid; i < N; i += 256) {
            float yc  = y_class[i];
            float ypc = y_pred_class[i];
            float nrm = (ypc - m) * inv2s + 0.5f;
            nrm = fminf(fmaxf(nrm, 0.0f), 1.0f);
            float c1  = (1.0f - yc) * nrm;
            float cwf = c1 * c1;                    // GAMMA = 2
            float x = fminf(fmaxf(output[i], FEPS), 1.0f - FEPS);
            float t = target[i];
            float bce = -t * logf(x) - (1.0f - t) * logf(1.0f - x);
            s_cwf  += (double)cwf;
            s_cwfb += (double)cwf * (double)bce;
        }
        double t_cwf  = block_reduce(s_cwf);
        double t_cwfb = block_reduce(s_cwfb);
        if (tid == 0) wd[0] = t_cwfb * (s_sum1myc / t_cwf) / (double)N;
    }

    // ---- pass 1: 4 rows/thread, 64 j-lanes/row ----
    const int lane = tid & 63;
    const int g    = tid >> 6;              // 0..3
    const int i0   = b * RPB + g * 4;
    float a0 = s1[i0+0], a1 = s1[i0+1], a2 = s1[i0+2], a3 = s1[i0+3];
    float e0 = s2[i0+0], e1 = s2[i0+1], e2 = s2[i0+2], e3 = s2[i0+3];
    float sa0=0.f,sa1=0.f,sa2=0.f,sa3=0.f, sb0=0.f,sb1=0.f,sb2=0.f,sb3=0.f;
#pragma unroll 4
    for (int k = 0; k < N / (64 * 4); ++k) {    // 16 float4 steps
        int j = 4 * lane + 256 * k;
        float4 x1 = *(const float4*)&s1[j];
        float4 x2 = *(const float4*)&s2[j];
        float4 xw = *(const float4*)&sw[j];
#define P1(c)                                      \
        sa0 = fmaf(fabsf(a0 - x1.c), xw.c, sa0);   \
        sa1 = fmaf(fabsf(a1 - x1.c), xw.c, sa1);   \
        sa2 = fmaf(fabsf(a2 - x1.c), xw.c, sa2);   \
        sa3 = fmaf(fabsf(a3 - x1.c), xw.c, sa3);   \
        sb0 = fmaf(fabsf(e0 - x2.c), xw.c, sb0);   \
        sb1 = fmaf(fabsf(e1 - x2.c), xw.c, sb1);   \
        sb2 = fmaf(fabsf(e2 - x2.c), xw.c, sb2);   \
        sb3 = fmaf(fabsf(e3 - x2.c), xw.c, sb3);
        P1(x) P1(y) P1(z) P1(w)
#undef P1
    }
#pragma unroll
    for (int o = 1; o < 64; o <<= 1) {
        sa0 += __shfl_xor(sa0, o, 64); sa1 += __shfl_xor(sa1, o, 64);
        sa2 += __shfl_xor(sa2, o, 64); sa3 += __shfl_xor(sa3, o, 64);
        sb0 += __shfl_xor(sb0, o, 64); sb1 += __shfl_xor(sb1, o, 64);
        sb2 += __shfl_xor(sb2, o, 64); sb3 += __shfl_xor(sb3, o, 64);
    }
    if (lane == 0) {
        rowA[i0+0]=sa0; rowA[i0+1]=sa1; rowA[i0+2]=sa2; rowA[i0+3]=sa3;
        rowB[i0+0]=sb0; rowB[i0+1]=sb1; rowB[i0+2]=sb2; rowB[i0+3]=sb3;
        rsA[g*4+0]=sa0; rsA[g*4+1]=sa1; rsA[g*4+2]=sa2; rsA[g*4+3]=sa3;
        rsB[g*4+0]=sb0; rsB[g*4+1]=sb1; rsB[g*4+2]=sb2; rsB[g*4+3]=sb3;
    }
    __syncthreads();   // rsA ready; all waves' rowA stores drained (vmcnt)

    // ---- inter-block barrier (tid0 only; scoped atomics, no bulk fences) ----
    if (tid == 0) {
        double ga = 0.0, gb = 0.0;
#pragma unroll
        for (int q = 0; q < RPB; ++q) {
            double wq = (double)sw[b * RPB + q];
            ga += (double)rsA[q] * wq;
            gb += (double)rsB[q] * wq;
        }
        pg[b] = ga; pg[NBLK + b] = gb;
        __hip_atomic_fetch_add(cntA, 1u, __ATOMIC_RELEASE, __HIP_MEMORY_SCOPE_AGENT);
        while (__hip_atomic_load(cntA, __ATOMIC_RELAXED, __HIP_MEMORY_SCOPE_AGENT) < NBLK)
            __builtin_amdgcn_s_sleep(2);
        (void)__hip_atomic_load(cntA, __ATOMIC_ACQUIRE, __HIP_MEMORY_SCOPE_AGENT);
    }
    __syncthreads();

    // ---- grand means (redundant per block; 4KB broadcast) ----
    const double NN = (double)N * (double)N;
    float gA = (float)(block_reduce(pg[tid]) / NN);
    float gB = (float)(block_reduce(pg[NBLK + tid]) / NN);

    // ---- stage row means ----
    const float invN = 1.0f / (float)N;
    for (int t = tid * 4; t < N; t += 1024) {
        float4 ra = *(const float4*)&rowA[t];
        float4 rb = *(const float4*)&rowB[t];
        ra.x *= invN; ra.y *= invN; ra.z *= invN; ra.w *= invN;
        rb.x *= invN; rb.y *= invN; rb.z *= invN; rb.w *= invN;
        *(float4*)&sav[t] = ra;
        *(float4*)&sbv[t] = rb;
    }
    __syncthreads();

    // ---- pass 2 ----
    float cA0 = sav[i0+0] - gA, cA1 = sav[i0+1] - gA,
          cA2 = sav[i0+2] - gA, cA3 = sav[i0+3] - gA;
    float cB0 = sbv[i0+0] - gB, cB1 = sbv[i0+1] - gB,
          cB2 = sbv[i0+2] - gB, cB3 = sbv[i0+3] - gB;

    float ab0=0.f,ab1=0.f,ab2=0.f,ab3=0.f;
    float aa0=0.f,aa1=0.f,aa2=0.f,aa3=0.f;
    float bb0=0.f,bb1=0.f,bb2=0.f,bb3=0.f;
#pragma unroll 2
    for (int k = 0; k < N / (64 * 4); ++k) {    // 16 float4 steps
        int j = 4 * lane + 256 * k;
        float4 x1 = *(const float4*)&s1[j];
        float4 x2 = *(const float4*)&s2[j];
        float4 xw = *(const float4*)&sw[j];
        float4 xa = *(const float4*)&sav[j];
        float4 xb = *(const float4*)&sbv[j];
#define P2(c, r)                                                  \
        {                                                         \
            float Am = fabsf(a##r - x1.c) - xa.c - cA##r;         \
            float Bm = fabsf(e##r - x2.c) - xb.c - cB##r;         \
            float Aw = Am * xw.c;                                 \
            float Bw = Bm * xw.c;                                 \
            ab##r = fmaf(Aw, Bm, ab##r);                          \
            aa##r = fmaf(Aw, Am, aa##r);                          \
            bb##r = fmaf(Bw, Bm, bb##r);                          \
        }
#define P2ALL(c) P2(c,0) P2(c,1) P2(c,2) P2(c,3)
        P2ALL(x) P2ALL(y) P2ALL(z) P2ALL(w)
#undef P2ALL
#undef P2
    }
#pragma unroll
    for (int o = 1; o < 64; o <<= 1) {
        ab0 += __shfl_xor(ab0, o, 64); ab1 += __shfl_xor(ab1, o, 64);
        ab2 += __shfl_xor(ab2, o, 64); ab3 += __shfl_xor(ab3, o, 64);
        aa0 += __shfl_xor(aa0, o, 64); aa1 += __shfl_xor(aa1, o, 64);
        aa2 += __shfl_xor(aa2, o, 64); aa3 += __shfl_xor(aa3, o, 64);
        bb0 += __shfl_xor(bb0, o, 64); bb1 += __shfl_xor(bb1, o, 64);
        bb2 += __shfl_xor(bb2, o, 64); bb3 += __shfl_xor(bb3, o, 64);
    }
    if (lane == 0) {
        double w0 = (double)sw[i0+0], w1 = (double)sw[i0+1];
        double w2 = (double)sw[i0+2], w3 = (double)sw[i0+3];
        rd[0][g*4+0] = fabs((double)ab0) * w0; rd[0][g*4+1] = fabs((double)ab1) * w1;
        rd[0][g*4+2] = fabs((double)ab2) * w2; rd[0][g*4+3] = fabs((double)ab3) * w3;
        rd[1][g*4+0] = (double)aa0 * w0;       rd[1][g*4+1] = (double)aa1 * w1;
        rd[1][g*4+2] = (double)aa2 * w2;       rd[1][g*4+3] = (double)aa3 * w3;
        rd[2][g*4+0] = (double)bb0 * w0;       rd[2][g*4+1] = (double)bb1 * w1;
        rd[2][g*4+2] = (double)bb2 * w2;       rd[2][g*4+3] = (double)bb3 * w3;
    }
    __syncthreads();

    // ---- last-block-done final reduction ----
    __shared__ int isLast;
    if (tid == 0) {
        double tab = 0.0, taa = 0.0, tbb = 0.0;
#pragma unroll
        for (int q = 0; q < RPB; ++q) { tab += rd[0][q]; taa += rd[1][q]; tbb += rd[2][q]; }
        pr[b] = tab; pr[NBLK + b] = taa; pr[2 * NBLK + b] = tbb;
        unsigned int old = __hip_atomic_fetch_add(cntB, 1u, __ATOMIC_ACQ_REL,
                                                  __HIP_MEMORY_SCOPE_AGENT);
        isLast = (old == NBLK - 1);
    }
    __syncthreads();
    if (!isLast) return;

    double tab = block_reduce(pr[tid]);
    double taa = block_reduce(pr[NBLK + tid]);
    double tbb = block_reduce(pr[2 * NBLK + tid]);
    if (tid == 0) {
        double mAB = tab / NN;
        double mAA = taa / NN;
        double mBB = tbb / NN;
        int p = power[0];
        double d;
        if (p == 1) {
            d = mAB / sqrt(fabs(mAA * mBB) + 1e-12);
        } else if (p == 2) {
            d = (mAB * mAB) / (fabs(mAA * mBB) + 1e-12);
        } else {
            d = pow(mAB / sqrt(mAA * mBB) + 1e-12, (double)p);
        }
        if (isnan(d)) d = 0.0;
        if (d < 0.0)  d = 0.0;
        out[0] = (float)(wd[0] + 1000.0 * d);
    }
}

// ---------------------------------------------------------------------------
extern "C" void kernel_launch(void* const* d_in, const int* in_sizes, int n_in,
                              void* d_out, int out_size, void* d_ws, size_t ws_size,
                              hipStream_t stream) {
    const float* target       = (const float*)d_in[0];
    const float* output       = (const float*)d_in[1];
    const float* y_class      = (const float*)d_in[2];
    const float* y_pred_class = (const float*)d_in[3];
    const float* var_1        = (const float*)d_in[4];
    const float* var_2        = (const float*)d_in[5];
    const float* normedweight = (const float*)d_in[6];
    const int*   power        = (const int*)d_in[7];
    float* out = (float*)d_out;

    char*         ws   = (char*)d_ws;
    unsigned int* cntA = (unsigned int*)ws;
    unsigned int* cntB = (unsigned int*)(ws + 4);
    double*       wd   = (double*)(ws + 8);
    double*       pg   = (double*)(ws + 64);            // 512 doubles
    double*       pr   = (double*)(ws + 64 + 4096);     // 768 doubles
    float*        rowA = (float*)(ws + 64 + 4096 + 6144);
    float*        rowB = rowA + N;

    hipMemsetAsync(ws, 0, 8, stream);                   // zero both counters
    fused<<<NBLK, 256, 0, stream>>>(target, output, y_class, y_pred_class,
                                    var_1, var_2, normedweight, power,
                                    cntA, cntB, wd, pg, pr, rowA, rowB, out);
}

// Round 6
// 36.481 us; speedup vs baseline: 3.1622x; 1.2432x over previous
//
#include <hip/hip_runtime.h>
#include <math.h>

#define N     4096
#define NBLK  256
#define RPB   16          // rows per block
#define FEPS  1e-7f

// ---------------------------------------------------------------------------
// ws layout (bytes):
//   [0,4)                 uint cntB (last-block-done; zeroed by memset node)
//   [64, +6144)           double pf[768]   (Sypc, Sypc2, Syc per block)
//   [6208, +4096)         double pg[512]   (gA partials, gB partials)
//   [10304, +10240)       double pr[1280]  (AB, AA, BB, cwf, cwfb per block)
//   [20544, +16384)       float rowA[N]
//   [36928, +16384)       float rowB[N]
// ---------------------------------------------------------------------------

__device__ __forceinline__ double block_reduce(double v) {
    __shared__ double buf[4];
    int tid = threadIdx.x;
#pragma unroll
    for (int o = 32; o > 0; o >>= 1) v += __shfl_down(v, o, 64);
    __syncthreads();
    if ((tid & 63) == 0) buf[tid >> 6] = v;
    __syncthreads();
    return buf[0] + buf[1] + buf[2] + buf[3];
}

// ---------------------------------------------------------------------------
// K1: pass-1 row sums + per-block focal stage-1 partials (no serial block)
// ---------------------------------------------------------------------------
__global__ __launch_bounds__(256) void k1(
        const float* __restrict__ y_class,
        const float* __restrict__ y_pred_class,
        const float* __restrict__ v1,
        const float* __restrict__ v2,
        const float* __restrict__ w,
        double* __restrict__ pf,
        double* __restrict__ pg,
        float*  __restrict__ rowA,
        float*  __restrict__ rowB)
{
    __shared__ float s1[N], s2[N], sw[N];     // 48 KiB
    __shared__ float rsA[RPB], rsB[RPB];
    const int tid = threadIdx.x;
    const int b   = blockIdx.x;

    // stage inputs
    for (int t = tid * 4; t < N; t += 1024) {
        *(float4*)&s1[t] = *(const float4*)&v1[t];
        *(float4*)&s2[t] = *(const float4*)&v2[t];
        *(float4*)&sw[t] = *(const float4*)&w [t];
    }

    // focal stage-1 partials: this block's 16 elements (first wave, shfl-16)
    if (tid < 16) {
        int i = b * RPB + tid;
        float ypc = y_pred_class[i];
        float yc  = y_class[i];
        double sy  = (double)ypc;
        double sy2 = (double)ypc * (double)ypc;
        double syc = (double)yc;
#pragma unroll
        for (int o = 1; o < 16; o <<= 1) {
            sy  += __shfl_xor(sy,  o, 16);
            sy2 += __shfl_xor(sy2, o, 16);
            syc += __shfl_xor(syc, o, 16);
        }
        if (tid == 0) { pf[b] = sy; pf[NBLK + b] = sy2; pf[2 * NBLK + b] = syc; }
    }
    __syncthreads();

    // pass 1: 4 rows/thread, 64 j-lanes/row
    const int lane = tid & 63;
    const int g    = tid >> 6;
    const int i0   = b * RPB + g * 4;
    float a0 = s1[i0+0], a1 = s1[i0+1], a2 = s1[i0+2], a3 = s1[i0+3];
    float e0 = s2[i0+0], e1 = s2[i0+1], e2 = s2[i0+2], e3 = s2[i0+3];
    float sa0=0.f,sa1=0.f,sa2=0.f,sa3=0.f, sb0=0.f,sb1=0.f,sb2=0.f,sb3=0.f;
#pragma unroll 4
    for (int k = 0; k < N / (64 * 4); ++k) {
        int j = 4 * lane + 256 * k;
        float4 x1 = *(const float4*)&s1[j];
        float4 x2 = *(const float4*)&s2[j];
        float4 xw = *(const float4*)&sw[j];
#define P1(c)                                      \
        sa0 = fmaf(fabsf(a0 - x1.c), xw.c, sa0);   \
        sa1 = fmaf(fabsf(a1 - x1.c), xw.c, sa1);   \
        sa2 = fmaf(fabsf(a2 - x1.c), xw.c, sa2);   \
        sa3 = fmaf(fabsf(a3 - x1.c), xw.c, sa3);   \
        sb0 = fmaf(fabsf(e0 - x2.c), xw.c, sb0);   \
        sb1 = fmaf(fabsf(e1 - x2.c), xw.c, sb1);   \
        sb2 = fmaf(fabsf(e2 - x2.c), xw.c, sb2);   \
        sb3 = fmaf(fabsf(e3 - x2.c), xw.c, sb3);
        P1(x) P1(y) P1(z) P1(w)
#undef P1
    }
#pragma unroll
    for (int o = 1; o < 64; o <<= 1) {
        sa0 += __shfl_xor(sa0, o, 64); sa1 += __shfl_xor(sa1, o, 64);
        sa2 += __shfl_xor(sa2, o, 64); sa3 += __shfl_xor(sa3, o, 64);
        sb0 += __shfl_xor(sb0, o, 64); sb1 += __shfl_xor(sb1, o, 64);
        sb2 += __shfl_xor(sb2, o, 64); sb3 += __shfl_xor(sb3, o, 64);
    }
    if (lane == 0) {
        rowA[i0+0]=sa0; rowA[i0+1]=sa1; rowA[i0+2]=sa2; rowA[i0+3]=sa3;
        rowB[i0+0]=sb0; rowB[i0+1]=sb1; rowB[i0+2]=sb2; rowB[i0+3]=sb3;
        rsA[g*4+0]=sa0; rsA[g*4+1]=sa1; rsA[g*4+2]=sa2; rsA[g*4+3]=sa3;
        rsB[g*4+0]=sb0; rsB[g*4+1]=sb1; rsB[g*4+2]=sb2; rsB[g*4+3]=sb3;
    }
    __syncthreads();
    if (tid == 0) {
        double ga = 0.0, gb = 0.0;
#pragma unroll
        for (int q = 0; q < RPB; ++q) {
            double wq = (double)sw[b * RPB + q];
            ga += (double)rsA[q] * wq;
            gb += (double)rsB[q] * wq;
        }
        pg[b] = ga; pg[NBLK + b] = gb;
    }
}

// ---------------------------------------------------------------------------
// K2: pass-2 centered products + distributed focal stage-2 + last-block final
// ---------------------------------------------------------------------------
__global__ __launch_bounds__(256) void k2(
        const float* __restrict__ target,
        const float* __restrict__ output,
        const float* __restrict__ y_class,
        const float* __restrict__ y_pred_class,
        const float* __restrict__ v1,
        const float* __restrict__ v2,
        const float* __restrict__ w,
        const float* __restrict__ rowA,
        const float* __restrict__ rowB,
        const double* __restrict__ pf,
        const double* __restrict__ pg,
        const int*   __restrict__ power,
        unsigned int* __restrict__ cntB,
        double* __restrict__ pr,
        float*  __restrict__ out)
{
    __shared__ float s1[N], s2[N], sw[N], sav[N], sbv[N];   // 80 KiB
    __shared__ double rd[3][RPB];
    const int tid = threadIdx.x;
    const int b   = blockIdx.x;
    const float invN = 1.0f / (float)N;

    // stage inputs + row means
    for (int t = tid * 4; t < N; t += 1024) {
        *(float4*)&s1[t] = *(const float4*)&v1[t];
        *(float4*)&s2[t] = *(const float4*)&v2[t];
        *(float4*)&sw[t] = *(const float4*)&w [t];
        float4 ra = *(const float4*)&rowA[t];
        float4 rb = *(const float4*)&rowB[t];
        ra.x *= invN; ra.y *= invN; ra.z *= invN; ra.w *= invN;
        rb.x *= invN; rb.y *= invN; rb.z *= invN; rb.w *= invN;
        *(float4*)&sav[t] = ra;
        *(float4*)&sbv[t] = rb;
    }
    __syncthreads();

    // grand reductions (redundant per block; pf/pg are 10KB, L2-hit)
    const double NN = (double)N * (double)N;
    float gA = (float)(block_reduce(pg[tid]) / NN);
    float gB = (float)(block_reduce(pg[NBLK + tid]) / NN);
    double t_ypc  = block_reduce(pf[tid]);
    double t_ypc2 = block_reduce(pf[NBLK + tid]);
    // m, sd for focal
    double fm   = t_ypc / (double)N;
    double fvar = t_ypc2 / (double)N - fm * fm;
    double fsd  = sqrt(fvar > 0.0 ? fvar : 0.0);
    float  m    = (float)fm;
    float  inv2s = (float)(1.0 / (2.0 * fsd));

    // focal stage-2 partials: this block's 16 elements (first wave, shfl-16)
    if (tid < 16) {
        int i = b * RPB + tid;
        float yc  = y_class[i];
        float ypc = y_pred_class[i];
        float nrm = (ypc - m) * inv2s + 0.5f;
        nrm = fminf(fmaxf(nrm, 0.0f), 1.0f);
        float c1  = (1.0f - yc) * nrm;
        float cwf = c1 * c1;                       // GAMMA = 2
        float x = fminf(fmaxf(output[i], FEPS), 1.0f - FEPS);
        float t = target[i];
        float bce = -t * logf(x) - (1.0f - t) * logf(1.0f - x);
        double scwf  = (double)cwf;
        double scwfb = (double)cwf * (double)bce;
#pragma unroll
        for (int o = 1; o < 16; o <<= 1) {
            scwf  += __shfl_xor(scwf,  o, 16);
            scwfb += __shfl_xor(scwfb, o, 16);
        }
        if (tid == 0) { pr[3 * NBLK + b] = scwf; pr[4 * NBLK + b] = scwfb; }
    }

    // pass 2: 4 rows/thread
    const int lane = tid & 63;
    const int g    = tid >> 6;
    const int i0   = b * RPB + g * 4;
    float a0 = s1[i0+0], a1 = s1[i0+1], a2 = s1[i0+2], a3 = s1[i0+3];
    float e0 = s2[i0+0], e1 = s2[i0+1], e2 = s2[i0+2], e3 = s2[i0+3];
    float cA0 = sav[i0+0] - gA, cA1 = sav[i0+1] - gA,
          cA2 = sav[i0+2] - gA, cA3 = sav[i0+3] - gA;
    float cB0 = sbv[i0+0] - gB, cB1 = sbv[i0+1] - gB,
          cB2 = sbv[i0+2] - gB, cB3 = sbv[i0+3] - gB;

    float ab0=0.f,ab1=0.f,ab2=0.f,ab3=0.f;
    float aa0=0.f,aa1=0.f,aa2=0.f,aa3=0.f;
    float bb0=0.f,bb1=0.f,bb2=0.f,bb3=0.f;
#pragma unroll 2
    for (int k = 0; k < N / (64 * 4); ++k) {
        int j = 4 * lane + 256 * k;
        float4 x1 = *(const float4*)&s1[j];
        float4 x2 = *(const float4*)&s2[j];
        float4 xw = *(const float4*)&sw[j];
        float4 xa = *(const float4*)&sav[j];
        float4 xb = *(const float4*)&sbv[j];
#define P2(c, r)                                                  \
        {                                                         \
            float Am = fabsf(a##r - x1.c) - xa.c - cA##r;         \
            float Bm = fabsf(e##r - x2.c) - xb.c - cB##r;         \
            float Aw = Am * xw.c;                                 \
            float Bw = Bm * xw.c;                                 \
            ab##r = fmaf(Aw, Bm, ab##r);                          \
            aa##r = fmaf(Aw, Am, aa##r);                          \
            bb##r = fmaf(Bw, Bm, bb##r);                          \
        }
#define P2ALL(c) P2(c,0) P2(c,1) P2(c,2) P2(c,3)
        P2ALL(x) P2ALL(y) P2ALL(z) P2ALL(w)
#undef P2ALL
#undef P2
    }
#pragma unroll
    for (int o = 1; o < 64; o <<= 1) {
        ab0 += __shfl_xor(ab0, o, 64); ab1 += __shfl_xor(ab1, o, 64);
        ab2 += __shfl_xor(ab2, o, 64); ab3 += __shfl_xor(ab3, o, 64);
        aa0 += __shfl_xor(aa0, o, 64); aa1 += __shfl_xor(aa1, o, 64);
        aa2 += __shfl_xor(aa2, o, 64); aa3 += __shfl_xor(aa3, o, 64);
        bb0 += __shfl_xor(bb0, o, 64); bb1 += __shfl_xor(bb1, o, 64);
        bb2 += __shfl_xor(bb2, o, 64); bb3 += __shfl_xor(bb3, o, 64);
    }
    if (lane == 0) {
        double w0 = (double)sw[i0+0], w1 = (double)sw[i0+1];
        double w2 = (double)sw[i0+2], w3 = (double)sw[i0+3];
        rd[0][g*4+0] = fabs((double)ab0) * w0; rd[0][g*4+1] = fabs((double)ab1) * w1;
        rd[0][g*4+2] = fabs((double)ab2) * w2; rd[0][g*4+3] = fabs((double)ab3) * w3;
        rd[1][g*4+0] = (double)aa0 * w0;       rd[1][g*4+1] = (double)aa1 * w1;
        rd[1][g*4+2] = (double)aa2 * w2;       rd[1][g*4+3] = (double)aa3 * w3;
        rd[2][g*4+0] = (double)bb0 * w0;       rd[2][g*4+1] = (double)bb1 * w1;
        rd[2][g*4+2] = (double)bb2 * w2;       rd[2][g*4+3] = (double)bb3 * w3;
    }
    __syncthreads();

    // last-block-done final reduction
    __shared__ int isLast;
    if (tid == 0) {
        double tab = 0.0, taa = 0.0, tbb = 0.0;
#pragma unroll
        for (int q = 0; q < RPB; ++q) { tab += rd[0][q]; taa += rd[1][q]; tbb += rd[2][q]; }
        pr[b] = tab; pr[NBLK + b] = taa; pr[2 * NBLK + b] = tbb;
        __threadfence();
        unsigned int old = atomicAdd(cntB, 1u);
        isLast = (old == NBLK - 1);
    }
    __syncthreads();
    if (!isLast) return;
    __threadfence();

    double tab   = block_reduce(pr[tid]);
    double taa   = block_reduce(pr[NBLK + tid]);
    double tbb   = block_reduce(pr[2 * NBLK + tid]);
    double tcwf  = block_reduce(pr[3 * NBLK + tid]);
    double tcwfb = block_reduce(pr[4 * NBLK + tid]);
    double t_yc  = block_reduce(pf[2 * NBLK + tid]);
    if (tid == 0) {
        double focal = tcwfb * (((double)N - t_yc) / tcwf) / (double)N;
        double mAB = tab / NN;
        double mAA = taa / NN;
        double mBB = tbb / NN;
        int p = power[0];
        double d;
        if (p == 1) {
            d = mAB / sqrt(fabs(mAA * mBB) + 1e-12);
        } else if (p == 2) {
            d = (mAB * mAB) / (fabs(mAA * mBB) + 1e-12);
        } else {
            d = pow(mAB / sqrt(mAA * mBB) + 1e-12, (double)p);
        }
        if (isnan(d)) d = 0.0;
        if (d < 0.0)  d = 0.0;
        out[0] = (float)(focal + 1000.0 * d);
    }
}

// ---------------------------------------------------------------------------
extern "C" void kernel_launch(void* const* d_in, const int* in_sizes, int n_in,
                              void* d_out, int out_size, void* d_ws, size_t ws_size,
                              hipStream_t stream) {
    const float* target       = (const float*)d_in[0];
    const float* output       = (const float*)d_in[1];
    const float* y_class      = (const float*)d_in[2];
    const float* y_pred_class = (const float*)d_in[3];
    const float* var_1        = (const float*)d_in[4];
    const float* var_2        = (const float*)d_in[5];
    const float* normedweight = (const float*)d_in[6];
    const int*   power        = (const int*)d_in[7];
    float* out = (float*)d_out;

    char*         ws   = (char*)d_ws;
    unsigned int* cntB = (unsigned int*)ws;
    double*       pf   = (double*)(ws + 64);
    double*       pg   = (double*)(ws + 64 + 6144);
    double*       pr   = (double*)(ws + 64 + 6144 + 4096);
    float*        rowA = (float*)(ws + 64 + 6144 + 4096 + 10240);
    float*        rowB = rowA + N;

    hipMemsetAsync(ws, 0, 4, stream);   // zero cntB
    k1<<<NBLK, 256, 0, stream>>>(y_class, y_pred_class, var_1, var_2, normedweight,
                                 pf, pg, rowA, rowB);
    k2<<<NBLK, 256, 0, stream>>>(target, output, y_class, y_pred_class,
                                 var_1, var_2, normedweight, rowA, rowB,
                                 pf, pg, power, cntB, pr, out);
}

// Round 7
// 34.996 us; speedup vs baseline: 3.2964x; 1.0424x over previous
//
#include <hip/hip_runtime.h>
#include <math.h>

#define N     4096
#define HALF  2048
#define NB    512          // blocks per pass kernel: (rb, h) for k1, row-blocks for k2
#define FEPS  1e-7f

// ---------------------------------------------------------------------------
// ws layout (bytes):
//   [0,4)            uint cntB (zeroed by k1 block 0; published at k1 end)
//   [64, +6144)      double pf[768]    Sypc[256], Sypc2[256], Syc[256]
//   [6208, +8192)    double pg[1024]   gA partials[512], gB partials[512]
//   [14400, +16384)  double pr[2048]   AB[512], AA[512], BB[512], cwf[256], cwfb[256]
//   [30784, +32768)  float rowA_p[2N]  (half-0, half-1 partial row sums)
//   [63552, +32768)  float rowB_p[2N]
// ---------------------------------------------------------------------------

__device__ __forceinline__ double block_reduce(double v) {
    __shared__ double buf[4];
    int tid = threadIdx.x;
#pragma unroll
    for (int o = 32; o > 0; o >>= 1) v += __shfl_down(v, o, 64);
    __syncthreads();
    if ((tid & 63) == 0) buf[tid >> 6] = v;
    __syncthreads();
    return buf[0] + buf[1] + buf[2] + buf[3];
}

// ---------------------------------------------------------------------------
// K1: 512 blocks = (row-block rb<256 [16 rows], j-half h). 24KB LDS -> 4/CU.
//     Partial row sums + per-block grand-mean partials + focal stage-1.
// ---------------------------------------------------------------------------
__global__ __launch_bounds__(256) void k1(
        const float* __restrict__ y_class,
        const float* __restrict__ y_pred_class,
        const float* __restrict__ v1,
        const float* __restrict__ v2,
        const float* __restrict__ w,
        unsigned int* __restrict__ cntB,
        double* __restrict__ pf,
        double* __restrict__ pg,
        float*  __restrict__ rowA_p,
        float*  __restrict__ rowB_p)
{
    __shared__ float s1[HALF], s2[HALF], sw[HALF];   // 24 KiB
    __shared__ float rsA[16], rsB[16];
    const int tid = threadIdx.x;
    const int b   = blockIdx.x;
    const int rb  = b >> 1;
    const int h   = b & 1;
    const int j0  = h * HALF;

    if (b == 0 && tid == 0) *cntB = 0;   // published by kernel-end barrier

    for (int t = tid * 4; t < HALF; t += 1024) {
        *(float4*)&s1[t] = *(const float4*)&v1[j0 + t];
        *(float4*)&s2[t] = *(const float4*)&v2[j0 + t];
        *(float4*)&sw[t] = *(const float4*)&w [j0 + t];
    }

    // focal stage-1 partials (even blocks only; 16 elems each)
    if (h == 0 && tid < 16) {
        int i = rb * 16 + tid;
        float ypc = y_pred_class[i];
        float yc  = y_class[i];
        double sy  = (double)ypc;
        double sy2 = (double)ypc * (double)ypc;
        double syc = (double)yc;
#pragma unroll
        for (int o = 1; o < 16; o <<= 1) {
            sy  += __shfl_xor(sy,  o, 16);
            sy2 += __shfl_xor(sy2, o, 16);
            syc += __shfl_xor(syc, o, 16);
        }
        if (tid == 0) { pf[rb] = sy; pf[256 + rb] = sy2; pf[512 + rb] = syc; }
    }
    __syncthreads();

    // pass 1: 4 rows/thread, 64 j-lanes, j over this half
    const int lane = tid & 63;
    const int g    = tid >> 6;
    const int i0   = rb * 16 + g * 4;
    float a0 = v1[i0+0], a1 = v1[i0+1], a2 = v1[i0+2], a3 = v1[i0+3];
    float e0 = v2[i0+0], e1 = v2[i0+1], e2 = v2[i0+2], e3 = v2[i0+3];
    float sa0=0.f,sa1=0.f,sa2=0.f,sa3=0.f, sb0=0.f,sb1=0.f,sb2=0.f,sb3=0.f;
#pragma unroll
    for (int k = 0; k < HALF / (64 * 4); ++k) {      // 8 float4 steps
        int j = 4 * lane + 256 * k;
        float4 x1 = *(const float4*)&s1[j];
        float4 x2 = *(const float4*)&s2[j];
        float4 xw = *(const float4*)&sw[j];
#define P1(c)                                      \
        sa0 = fmaf(fabsf(a0 - x1.c), xw.c, sa0);   \
        sa1 = fmaf(fabsf(a1 - x1.c), xw.c, sa1);   \
        sa2 = fmaf(fabsf(a2 - x1.c), xw.c, sa2);   \
        sa3 = fmaf(fabsf(a3 - x1.c), xw.c, sa3);   \
        sb0 = fmaf(fabsf(e0 - x2.c), xw.c, sb0);   \
        sb1 = fmaf(fabsf(e1 - x2.c), xw.c, sb1);   \
        sb2 = fmaf(fabsf(e2 - x2.c), xw.c, sb2);   \
        sb3 = fmaf(fabsf(e3 - x2.c), xw.c, sb3);
        P1(x) P1(y) P1(z) P1(w)
#undef P1
    }
#pragma unroll
    for (int o = 1; o < 64; o <<= 1) {
        sa0 += __shfl_xor(sa0, o, 64); sa1 += __shfl_xor(sa1, o, 64);
        sa2 += __shfl_xor(sa2, o, 64); sa3 += __shfl_xor(sa3, o, 64);
        sb0 += __shfl_xor(sb0, o, 64); sb1 += __shfl_xor(sb1, o, 64);
        sb2 += __shfl_xor(sb2, o, 64); sb3 += __shfl_xor(sb3, o, 64);
    }
    if (lane == 0) {
        rowA_p[h*N + i0+0]=sa0; rowA_p[h*N + i0+1]=sa1;
        rowA_p[h*N + i0+2]=sa2; rowA_p[h*N + i0+3]=sa3;
        rowB_p[h*N + i0+0]=sb0; rowB_p[h*N + i0+1]=sb1;
        rowB_p[h*N + i0+2]=sb2; rowB_p[h*N + i0+3]=sb3;
        rsA[g*4+0]=sa0; rsA[g*4+1]=sa1; rsA[g*4+2]=sa2; rsA[g*4+3]=sa3;
        rsB[g*4+0]=sb0; rsB[g*4+1]=sb1; rsB[g*4+2]=sb2; rsB[g*4+3]=sb3;
    }
    __syncthreads();
    if (tid < 16) {                          // grand-mean partials (shfl-16)
        double wq = (double)w[rb * 16 + tid];
        double da = (double)rsA[tid] * wq;
        double db = (double)rsB[tid] * wq;
#pragma unroll
        for (int o = 1; o < 16; o <<= 1) {
            da += __shfl_xor(da, o, 16);
            db += __shfl_xor(db, o, 16);
        }
        if (tid == 0) { pg[b] = da; pg[NB + b] = db; }
    }
}

// ---------------------------------------------------------------------------
// K2: 512 blocks x 8 full rows (2 rows/thread), j staged in two halves.
//     40KB LDS -> 2-4/CU. + focal stage-2 + last-block final.
// ---------------------------------------------------------------------------
__global__ __launch_bounds__(256) void k2(
        const float* __restrict__ target,
        const float* __restrict__ output,
        const float* __restrict__ y_class,
        const float* __restrict__ y_pred_class,
        const float* __restrict__ v1,
        const float* __restrict__ v2,
        const float* __restrict__ w,
        const float* __restrict__ rowA_p,
        const float* __restrict__ rowB_p,
        const double* __restrict__ pf,
        const double* __restrict__ pg,
        const int*   __restrict__ power,
        unsigned int* __restrict__ cntB,
        double* __restrict__ pr,
        float*  __restrict__ out)
{
    __shared__ float s1[HALF], s2[HALF], sw[HALF], sav[HALF], sbv[HALF]; // 40 KiB
    __shared__ double rd[3][8];
    const int tid = threadIdx.x;
    const int b   = blockIdx.x;
    const float invN = 1.0f / (float)N;
    const double NN = (double)N * (double)N;

    // grand reductions (pf/pg ~14KB, L2-hot; redundant per block)
    float gA = (float)(block_reduce(pg[tid]      + pg[256 + tid]) / NN);
    float gB = (float)(block_reduce(pg[NB + tid] + pg[NB + 256 + tid]) / NN);
    double t_ypc  = block_reduce(pf[tid]);
    double t_ypc2 = block_reduce(pf[256 + tid]);
    double fm   = t_ypc / (double)N;
    double fvar = t_ypc2 / (double)N - fm * fm;
    double fsd  = sqrt(fvar > 0.0 ? fvar : 0.0);
    float  m     = (float)fm;
    float  inv2s = (float)(1.0 / (2.0 * fsd));

    // focal stage-2 partials (blocks < 256; 16 elems each)
    if (b < 256 && tid < 16) {
        int i = b * 16 + tid;
        float yc  = y_class[i];
        float ypc = y_pred_class[i];
        float nrm = (ypc - m) * inv2s + 0.5f;
        nrm = fminf(fmaxf(nrm, 0.0f), 1.0f);
        float c1  = (1.0f - yc) * nrm;
        float cwf = c1 * c1;                       // GAMMA = 2
        float x = fminf(fmaxf(output[i], FEPS), 1.0f - FEPS);
        float t = target[i];
        float bce = -t * logf(x) - (1.0f - t) * logf(1.0f - x);
        double scwf  = (double)cwf;
        double scwfb = (double)cwf * (double)bce;
#pragma unroll
        for (int o = 1; o < 16; o <<= 1) {
            scwf  += __shfl_xor(scwf,  o, 16);
            scwfb += __shfl_xor(scwfb, o, 16);
        }
        if (tid == 0) { pr[3 * NB + b] = scwf; pr[3 * NB + 256 + b] = scwfb; }
    }

    // pass 2: 2 rows/thread, 64 j-lanes, two staged halves
    const int lane = tid & 63;
    const int g    = tid >> 6;
    const int i0   = b * 8 + g * 2;
    float a0 = v1[i0+0], a1 = v1[i0+1];
    float e0 = v2[i0+0], e1 = v2[i0+1];
    float cA0 = (rowA_p[i0+0] + rowA_p[N+i0+0]) * invN - gA;
    float cA1 = (rowA_p[i0+1] + rowA_p[N+i0+1]) * invN - gA;
    float cB0 = (rowB_p[i0+0] + rowB_p[N+i0+0]) * invN - gB;
    float cB1 = (rowB_p[i0+1] + rowB_p[N+i0+1]) * invN - gB;

    float ab0=0.f,aa0=0.f,bb0=0.f, ab1=0.f,aa1=0.f,bb1=0.f;
    for (int h = 0; h < 2; ++h) {
        int j0 = h * HALF;
        __syncthreads();
        for (int t = tid * 4; t < HALF; t += 1024) {
            *(float4*)&s1[t] = *(const float4*)&v1[j0 + t];
            *(float4*)&s2[t] = *(const float4*)&v2[j0 + t];
            *(float4*)&sw[t] = *(const float4*)&w [j0 + t];
            float4 r0 = *(const float4*)&rowA_p[j0 + t];
            float4 r1 = *(const float4*)&rowA_p[N + j0 + t];
            float4 q0 = *(const float4*)&rowB_p[j0 + t];
            float4 q1 = *(const float4*)&rowB_p[N + j0 + t];
            float4 ra, rbv;
            ra.x  = (r0.x + r1.x) * invN;  ra.y  = (r0.y + r1.y) * invN;
            ra.z  = (r0.z + r1.z) * invN;  ra.w  = (r0.w + r1.w) * invN;
            rbv.x = (q0.x + q1.x) * invN;  rbv.y = (q0.y + q1.y) * invN;
            rbv.z = (q0.z + q1.z) * invN;  rbv.w = (q0.w + q1.w) * invN;
            *(float4*)&sav[t] = ra;
            *(float4*)&sbv[t] = rbv;
        }
        __syncthreads();
#pragma unroll
        for (int k = 0; k < HALF / (64 * 4); ++k) {   // 8 float4 steps
            int j = 4 * lane + 256 * k;
            float4 x1 = *(const float4*)&s1[j];
            float4 x2 = *(const float4*)&s2[j];
            float4 xw = *(const float4*)&sw[j];
            float4 xa = *(const float4*)&sav[j];
            float4 xb = *(const float4*)&sbv[j];
#define P2(c, r)                                                  \
            {                                                     \
                float Am = fabsf(a##r - x1.c) - xa.c - cA##r;     \
                float Bm = fabsf(e##r - x2.c) - xb.c - cB##r;     \
                float Aw = Am * xw.c;                             \
                float Bw = Bm * xw.c;                             \
                ab##r = fmaf(Aw, Bm, ab##r);                      \
                aa##r = fmaf(Aw, Am, aa##r);                      \
                bb##r = fmaf(Bw, Bm, bb##r);                      \
            }
#define P2ALL(c) P2(c,0) P2(c,1)
            P2ALL(x) P2ALL(y) P2ALL(z) P2ALL(w)
#undef P2ALL
#undef P2
        }
    }
#pragma unroll
    for (int o = 1; o < 64; o <<= 1) {
        ab0 += __shfl_xor(ab0, o, 64); ab1 += __shfl_xor(ab1, o, 64);
        aa0 += __shfl_xor(aa0, o, 64); aa1 += __shfl_xor(aa1, o, 64);
        bb0 += __shfl_xor(bb0, o, 64); bb1 += __shfl_xor(bb1, o, 64);
    }
    if (lane == 0) {
        double w0 = (double)w[i0+0], w1 = (double)w[i0+1];
        rd[0][g*2+0] = fabs((double)ab0) * w0;  rd[0][g*2+1] = fabs((double)ab1) * w1;
        rd[1][g*2+0] = (double)aa0 * w0;        rd[1][g*2+1] = (double)aa1 * w1;
        rd[2][g*2+0] = (double)bb0 * w0;        rd[2][g*2+1] = (double)bb1 * w1;
    }
    __syncthreads();

    __shared__ int isLast;
    if (tid == 0) {
        double tab = 0.0, taa = 0.0, tbb = 0.0;
#pragma unroll
        for (int q = 0; q < 8; ++q) { tab += rd[0][q]; taa += rd[1][q]; tbb += rd[2][q]; }
        pr[b] = tab; pr[NB + b] = taa; pr[2 * NB + b] = tbb;
        __threadfence();
        unsigned int old = atomicAdd(cntB, 1u);
        isLast = (old == NB - 1);
    }
    __syncthreads();
    if (!isLast) return;
    __threadfence();

    double tab   = block_reduce(pr[tid]          + pr[256 + tid]);
    double taa   = block_reduce(pr[NB + tid]     + pr[NB + 256 + tid]);
    double tbb   = block_reduce(pr[2*NB + tid]   + pr[2*NB + 256 + tid]);
    double tcwf  = block_reduce(pr[3*NB + tid]);
    double tcwfb = block_reduce(pr[3*NB + 256 + tid]);
    double t_yc  = block_reduce(pf[512 + tid]);
    if (tid == 0) {
        double focal = tcwfb * (((double)N - t_yc) / tcwf) / (double)N;
        double mAB = tab / NN;
        double mAA = taa / NN;
        double mBB = tbb / NN;
        int p = power[0];
        double d;
        if (p == 1) {
            d = mAB / sqrt(fabs(mAA * mBB) + 1e-12);
        } else if (p == 2) {
            d = (mAB * mAB) / (fabs(mAA * mBB) + 1e-12);
        } else {
            d = pow(mAB / sqrt(mAA * mBB) + 1e-12, (double)p);
        }
        if (isnan(d)) d = 0.0;
        if (d < 0.0)  d = 0.0;
        out[0] = (float)(focal + 1000.0 * d);
    }
}

// ---------------------------------------------------------------------------
extern "C" void kernel_launch(void* const* d_in, const int* in_sizes, int n_in,
                              void* d_out, int out_size, void* d_ws, size_t ws_size,
                              hipStream_t stream) {
    const float* target       = (const float*)d_in[0];
    const float* output       = (const float*)d_in[1];
    const float* y_class      = (const float*)d_in[2];
    const float* y_pred_class = (const float*)d_in[3];
    const float* var_1        = (const float*)d_in[4];
    const float* var_2        = (const float*)d_in[5];
    const float* normedweight = (const float*)d_in[6];
    const int*   power        = (const int*)d_in[7];
    float* out = (float*)d_out;

    char*         ws     = (char*)d_ws;
    unsigned int* cntB   = (unsigned int*)ws;
    double*       pf     = (double*)(ws + 64);
    double*       pg     = (double*)(ws + 64 + 6144);
    double*       pr     = (double*)(ws + 64 + 6144 + 8192);
    float*        rowA_p = (float*)(ws + 64 + 6144 + 8192 + 16384);
    float*        rowB_p = rowA_p + 2 * N;

    k1<<<NB, 256, 0, stream>>>(y_class, y_pred_class, var_1, var_2, normedweight,
                               cntB, pf, pg, rowA_p, rowB_p);
    k2<<<NB, 256, 0, stream>>>(target, output, y_class, y_pred_class,
                               var_1, var_2, normedweight, rowA_p, rowB_p,
                               pf, pg, power, cntB, pr, out);
}